// Round 1
// baseline (439.491 us; speedup 1.0000x reference)
//
#include <hip/hip_runtime.h>
#include <stdint.h>

#define DD 512
#define BB 16384
#define PR 17408      // 16384 + 8*128 worst-case bucket padding
#define MAXT 136      // PR/128

typedef short bf16x8 __attribute__((ext_vector_type(8)));
typedef float f32x4 __attribute__((ext_vector_type(4)));
typedef unsigned short us4v __attribute__((ext_vector_type(4)));

typedef __attribute__((address_space(1))) unsigned short gus_t;
typedef __attribute__((address_space(3))) unsigned short lus_t;

__device__ __forceinline__ unsigned short f2bf(float f) {
    unsigned int u = __float_as_uint(f);
    u += 0x7fffu + ((u >> 16) & 1u);   // RNE
    return (unsigned short)(u >> 16);
}
__device__ __forceinline__ float bf2f(unsigned short h) {
    return __uint_as_float(((unsigned int)h) << 16);
}

__device__ __forceinline__ void gld16(const unsigned short* g, unsigned short* l) {
    __builtin_amdgcn_global_load_lds(
        reinterpret_cast<const gus_t*>(reinterpret_cast<uintptr_t>(g)),
        reinterpret_cast<lus_t*>(reinterpret_cast<uintptr_t>(l)),
        16, 0, 0);
}

// ---------------- conversion ----------------
__global__ void cvt_bf16(const float* __restrict__ src, unsigned short* __restrict__ dst, int n4) {
    int stride = gridDim.x * blockDim.x;
    for (int i = blockIdx.x * blockDim.x + threadIdx.x; i < n4; i += stride) {
        f32x4 v = reinterpret_cast<const f32x4*>(src)[i];
        us4v o;
        o[0] = f2bf(v[0]); o[1] = f2bf(v[1]); o[2] = f2bf(v[2]); o[3] = f2bf(v[3]);
        reinterpret_cast<us4v*>(dst)[i] = o;
    }
}

// ---------------- bucketing ----------------
__global__ void bucket_init(int* perm, int* counts, int* cursors, int* tile_exp) {
    int i = blockIdx.x * blockDim.x + threadIdx.x;
    if (i < PR) perm[i] = -1;
    if (i < 8) { counts[i] = 0; cursors[i] = 0; }
    if (i < MAXT) tile_exp[i] = 0;
}

__global__ void bucket_count(const int* __restrict__ y, int* counts) {
    int i = blockIdx.x * blockDim.x + threadIdx.x;
    if (i < BB) atomicAdd(&counts[y[i]], 1);
}

__global__ void bucket_scan(const int* __restrict__ counts, int* starts, int* tile_exp) {
    if (threadIdx.x == 0 && blockIdx.x == 0) {
        int s = 0;
        for (int e = 0; e < 8; ++e) {
            starts[e] = s;
            int nt = (counts[e] + 127) >> 7;
            for (int t = 0; t < nt; ++t) tile_exp[(s >> 7) + t] = e;
            s += nt << 7;
        }
        starts[8] = s;   // total padded rows (multiple of 128)
    }
}

__global__ void bucket_scatter(const int* __restrict__ y, const int* __restrict__ starts,
                               int* cursors, int* perm) {
    int i = blockIdx.x * blockDim.x + threadIdx.x;
    if (i < BB) {
        int e = y[i];
        int pos = starts[e] + atomicAdd(&cursors[e], 1);
        perm[pos] = i;
    }
}

// ---------------- GEMM: C[M,512] = A[M,512] * W[512,512]^T (+bias, epilogue) ----------
// MODE 0: dense, relu -> bf16 out                       (dec layers 1-3)
// MODE 1: dense, relu -> h; srel=bf16(s-h); sunrel=bf16(h)   (dec layer 4)
// MODE 2: gather rows via perm, expert W, relu -> bf16 out   (exp layer 1)
// MODE 3: dense perm-space, expert W, relu -> bf16 out       (exp layers 2,3)
// MODE 4: dense perm-space, expert W, no relu, += sunrel, scatter f32 to d_out (exp layer 4)
template <int MODE>
__global__ __launch_bounds__(256) void gemm_k(
    const unsigned short* __restrict__ A,
    const unsigned short* __restrict__ W,
    const float* __restrict__ bias,
    unsigned short* __restrict__ outb,
    unsigned short* __restrict__ outb2,
    const float* __restrict__ sf32,
    float* __restrict__ outf,
    const unsigned short* __restrict__ sunrel,
    const int* __restrict__ perm,
    const int* __restrict__ tile_exp,
    const int* __restrict__ nrows_ptr,
    int layer)
{
    const int tm = blockIdx.x;
    const int tn = blockIdx.y;
    if (MODE >= 2) {
        if ((tm << 7) >= nrows_ptr[0]) return;   // tile fully padding
    }
    const unsigned short* Wl = W;
    const float* bl = bias;
    if (MODE >= 2) {
        const int e = tile_exp[tm];
        const int li = e * 4 + layer;
        Wl = W + ((size_t)li << 18);     // *512*512
        bl = bias + (li << 9);           // *512
    }
    const int tid = threadIdx.x;
    const int srow = tid & 127;
    const int kb = tid >> 7;             // 0/1: which k-subblock this thread stages

    size_t arow;
    if (MODE == 2) {
        const int p = perm[(tm << 7) + srow];
        arow = ((size_t)(p < 0 ? 0 : p)) << 9;
    } else {
        arow = ((size_t)((tm << 7) + srow)) << 9;
    }
    const unsigned short* Ap = A + arow;
    const unsigned short* Wp = Wl + (((size_t)((tn << 7) + srow)) << 9);

    // k-blocked LDS layout: elem offset (row,k) = (k>>3)*1024 + row*8 + (k&7)
    // -> ds_read_b128 of a fragment is bank-conflict-free (2 lanes/bank)
    __shared__ __align__(16) unsigned short lsA[8192];
    __shared__ __align__(16) unsigned short lsB[8192];

    f32x4 acc[4][4];
#pragma unroll
    for (int i = 0; i < 4; ++i)
#pragma unroll
        for (int j = 0; j < 4; ++j)
            acc[i][j] = f32x4{0.f, 0.f, 0.f, 0.f};

    const int lane = tid & 63;
    const int wv = tid >> 6;
    const int wm = wv >> 1;
    const int wn = wv & 1;
    const int lr = lane & 15;
    const int kg = lane >> 4;
    const int r0 = (wm << 6) + lr;
    const int c0 = (wn << 6) + lr;

    for (int ko = 0; ko < 8; ++ko) {
        __syncthreads();
        const int kcol = ko << 6;
#pragma unroll
        for (int c = 0; c < 4; ++c) {
            const int k0 = kcol + ((2 * c + kb) << 3);    // global k of this 16B chunk
            const int lo = (c << 11) + (tid << 3);        // linear LDS dest (lane-ordered)
            gld16(Ap + k0, &lsA[lo]);
            gld16(Wp + k0, &lsB[lo]);
        }
        __syncthreads();
#pragma unroll
        for (int kk = 0; kk < 2; ++kk) {
            const int kbo = (((kk << 2) + kg) << 10);     // k-block base (elems)
            bf16x8 af[4], bv[4];
#pragma unroll
            for (int i = 0; i < 4; ++i)
                af[i] = *reinterpret_cast<const bf16x8*>(&lsA[kbo + ((r0 + (i << 4)) << 3)]);
#pragma unroll
            for (int j = 0; j < 4; ++j)
                bv[j] = *reinterpret_cast<const bf16x8*>(&lsB[kbo + ((c0 + (j << 4)) << 3)]);
#pragma unroll
            for (int i = 0; i < 4; ++i)
#pragma unroll
                for (int j = 0; j < 4; ++j)
                    acc[i][j] = __builtin_amdgcn_mfma_f32_16x16x32_bf16(af[i], bv[j], acc[i][j], 0, 0, 0);
        }
    }

    // epilogue; D layout: col = lane&15, row = (lane>>4)*4 + reg   [m89 verified]
    const int colb = (tn << 7) + (wn << 6);
    const int rowb = (tm << 7) + (wm << 6);
#pragma unroll
    for (int j = 0; j < 4; ++j) {
        const int col = colb + (j << 4) + lr;
        const float bj = bl[col];
#pragma unroll
        for (int i = 0; i < 4; ++i) {
            const int rb = rowb + (i << 4) + (kg << 2);
#pragma unroll
            for (int r = 0; r < 4; ++r) {
                const int row = rb + r;
                float v = acc[i][j][r] + bj;
                if (MODE == 0 || MODE == 2 || MODE == 3) {
                    v = fmaxf(v, 0.f);
                    outb[((size_t)row << 9) + col] = f2bf(v);
                } else if (MODE == 1) {
                    v = fmaxf(v, 0.f);                       // h = s_unrelated
                    const size_t gi = ((size_t)row << 9) + col;
                    const float sv = sf32[gi];
                    outb[gi] = f2bf(sv - v);                 // s_related
                    outb2[gi] = f2bf(v);                     // s_unrelated
                } else {                                     // MODE 4
                    const int b = perm[row];
                    if (b >= 0) {
                        const size_t gi = ((size_t)b << 9) + col;
                        outf[gi] = v + bf2f(sunrel[gi]);
                    }
                }
            }
        }
    }
}

// ---------------- launch ----------------
extern "C" void kernel_launch(void* const* d_in, const int* in_sizes, int n_in,
                              void* d_out, int out_size, void* d_ws, size_t ws_size,
                              hipStream_t stream)
{
    const float* s     = (const float*)d_in[0];
    const int*   y     = (const int*)d_in[1];
    const float* dec_W = (const float*)d_in[2];
    const float* dec_b = (const float*)d_in[3];
    const float* exp_W = (const float*)d_in[4];
    const float* exp_b = (const float*)d_in[5];
    float* out = (float*)d_out;

    // workspace carve (~72.4 MB total)
    unsigned short* decWb = (unsigned short*)d_ws;              // 4*512*512 bf16
    unsigned short* expWb = decWb + 4 * 512 * 512;              // 32*512*512 bf16
    unsigned short* bufS  = expWb + 8 * 4 * 512 * 512;          // PR*512 bf16 (s_bf -> s_rel -> scratch)
    unsigned short* bufA  = bufS + (size_t)PR * 512;            // PR*512 bf16
    unsigned short* bufB  = bufA + (size_t)PR * 512;            // PR*512 bf16 (-> s_unrel)
    int* perm     = (int*)(bufB + (size_t)PR * 512);            // PR
    int* counts   = perm + PR;                                  // 8
    int* cursors  = counts + 8;                                 // 8
    int* starts   = cursors + 8;                                // 9 (starts[8]=total padded rows)
    int* tile_exp = starts + 9;                                 // MAXT

    cvt_bf16<<<512, 256, 0, stream>>>(dec_W, decWb, (4 * 512 * 512) / 4);
    cvt_bf16<<<2048, 256, 0, stream>>>(exp_W, expWb, (8 * 4 * 512 * 512) / 4);
    cvt_bf16<<<2048, 256, 0, stream>>>(s, bufS, (BB * 512) / 4);

    bucket_init<<<PR / 256, 256, 0, stream>>>(perm, counts, cursors, tile_exp);
    bucket_count<<<BB / 256, 256, 0, stream>>>(y, counts);
    bucket_scan<<<1, 64, 0, stream>>>(counts, starts, tile_exp);
    bucket_scatter<<<BB / 256, 256, 0, stream>>>(y, starts, cursors, perm);

    dim3 blk(256);
    dim3 gdec(BB / 128, 4);
    dim3 gexp(MAXT, 4);

    // decomposer: bufS -> bufA -> bufB -> bufA -> (s_rel in bufS, s_unrel in bufB)
    gemm_k<0><<<gdec, blk, 0, stream>>>(bufS, decWb, dec_b, bufA,
                                        nullptr, nullptr, nullptr, nullptr, nullptr, nullptr, nullptr, 0);
    gemm_k<0><<<gdec, blk, 0, stream>>>(bufA, decWb + (1u << 18), dec_b + 512, bufB,
                                        nullptr, nullptr, nullptr, nullptr, nullptr, nullptr, nullptr, 0);
    gemm_k<0><<<gdec, blk, 0, stream>>>(bufB, decWb + (2u << 18), dec_b + 1024, bufA,
                                        nullptr, nullptr, nullptr, nullptr, nullptr, nullptr, nullptr, 0);
    gemm_k<1><<<gdec, blk, 0, stream>>>(bufA, decWb + (3u << 18), dec_b + 1536, bufS,
                                        bufB, s, nullptr, nullptr, nullptr, nullptr, nullptr, 0);

    // experts (selected expert only, bucketed): gather bufS -> bufA -> bufS -> bufA -> d_out
    gemm_k<2><<<gexp, blk, 0, stream>>>(bufS, expWb, exp_b, bufA,
                                        nullptr, nullptr, nullptr, nullptr, perm, tile_exp, starts + 8, 0);
    gemm_k<3><<<gexp, blk, 0, stream>>>(bufA, expWb, exp_b, bufS,
                                        nullptr, nullptr, nullptr, nullptr, perm, tile_exp, starts + 8, 1);
    gemm_k<3><<<gexp, blk, 0, stream>>>(bufS, expWb, exp_b, bufA,
                                        nullptr, nullptr, nullptr, nullptr, perm, tile_exp, starts + 8, 2);
    gemm_k<4><<<gexp, blk, 0, stream>>>(bufA, expWb, exp_b, nullptr,
                                        nullptr, nullptr, out, bufB, perm, tile_exp, starts + 8, 3);
}

// Round 2
// 297.090 us; speedup vs baseline: 1.4793x; 1.4793x over previous
//
#include <hip/hip_runtime.h>
#include <stdint.h>

#define DD 512
#define BB 16384
#define PR 17408      // 16384 + 8*128 worst-case bucket padding
#define MAXT 136      // PR/128

typedef short bf16x8 __attribute__((ext_vector_type(8)));
typedef float f32x4 __attribute__((ext_vector_type(4)));
typedef unsigned short us4v __attribute__((ext_vector_type(4)));

typedef __attribute__((address_space(1))) unsigned short gus_t;
typedef __attribute__((address_space(3))) unsigned short lus_t;

__device__ __forceinline__ unsigned short f2bf(float f) {
    unsigned int u = __float_as_uint(f);
    u += 0x7fffu + ((u >> 16) & 1u);   // RNE
    return (unsigned short)(u >> 16);
}
__device__ __forceinline__ float bf2f(unsigned short h) {
    return __uint_as_float(((unsigned int)h) << 16);
}

__device__ __forceinline__ void gld16(const unsigned short* g, unsigned short* l) {
    __builtin_amdgcn_global_load_lds(
        reinterpret_cast<const gus_t*>(reinterpret_cast<uintptr_t>(g)),
        reinterpret_cast<lus_t*>(reinterpret_cast<uintptr_t>(l)),
        16, 0, 0);
}

// ---------------- conversion ----------------
__global__ void cvt_bf16(const float* __restrict__ src, unsigned short* __restrict__ dst, int n4) {
    int stride = gridDim.x * blockDim.x;
    for (int i = blockIdx.x * blockDim.x + threadIdx.x; i < n4; i += stride) {
        f32x4 v = reinterpret_cast<const f32x4*>(src)[i];
        us4v o;
        o[0] = f2bf(v[0]); o[1] = f2bf(v[1]); o[2] = f2bf(v[2]); o[3] = f2bf(v[3]);
        reinterpret_cast<us4v*>(dst)[i] = o;
    }
}

// ---------------- bucketing (block-aggregated atomics, G12) ----------------
__global__ void bucket_init(int* perm, int* counts, int* cursors, int* tile_exp) {
    int i = blockIdx.x * blockDim.x + threadIdx.x;
    if (i < PR) perm[i] = -1;
    if (i < 8) { counts[i] = 0; cursors[i] = 0; }
    if (i < MAXT) tile_exp[i] = 0;
}

__global__ __launch_bounds__(1024) void bucket_count(const int* __restrict__ y, int* counts) {
    __shared__ int lc[8];
    const int t = threadIdx.x;
    if (t < 8) lc[t] = 0;
    __syncthreads();
    const int i = blockIdx.x * 1024 + t;           // grid covers BB exactly
    atomicAdd(&lc[y[i]], 1);
    __syncthreads();
    if (t < 8) atomicAdd(&counts[t], lc[t]);
}

__global__ void bucket_scan(const int* __restrict__ counts, int* starts, int* tile_exp) {
    if (threadIdx.x == 0 && blockIdx.x == 0) {
        int s = 0;
        for (int e = 0; e < 8; ++e) {
            starts[e] = s;
            int nt = (counts[e] + 127) >> 7;
            for (int t = 0; t < nt; ++t) tile_exp[(s >> 7) + t] = e;
            s += nt << 7;
        }
        starts[8] = s;   // total padded rows (multiple of 128)
    }
}

// rank-within-block via LDS atomic; one global atomic per expert per block.
// Order within a bucket is irrelevant (perm used symmetrically on both ends).
__global__ __launch_bounds__(1024) void bucket_scatter(const int* __restrict__ y,
                                                       const int* __restrict__ starts,
                                                       int* cursors, int* perm) {
    __shared__ int lc[8];
    __shared__ int lbase[8];
    const int t = threadIdx.x;
    if (t < 8) lc[t] = 0;
    __syncthreads();
    const int i = blockIdx.x * 1024 + t;           // grid covers BB exactly
    const int e = y[i];
    const int r = atomicAdd(&lc[e], 1);
    __syncthreads();
    if (t < 8) lbase[t] = atomicAdd(&cursors[t], lc[t]);
    __syncthreads();
    perm[starts[e] + lbase[e] + r] = i;
}

// ---------------- GEMM: C[M,512] = A[M,512] * W[512,512]^T (+bias, epilogue) ----------
// MODE 0: dense, relu -> bf16 out                       (dec layers 1-3)
// MODE 1: dense, relu -> h; srel=bf16(s-h); sunrel=bf16(h)   (dec layer 4)
// MODE 2: gather rows via perm, expert W, relu -> bf16 out   (exp layer 1)
// MODE 3: dense perm-space, expert W, relu -> bf16 out       (exp layers 2,3)
// MODE 4: dense perm-space, expert W, no relu, += sunrel, scatter f32 to d_out (exp layer 4)
template <int MODE>
__global__ __launch_bounds__(256) void gemm_k(
    const unsigned short* __restrict__ A,
    const unsigned short* __restrict__ W,
    const float* __restrict__ bias,
    unsigned short* __restrict__ outb,
    unsigned short* __restrict__ outb2,
    const float* __restrict__ sf32,
    float* __restrict__ outf,
    const unsigned short* __restrict__ sunrel,
    const int* __restrict__ perm,
    const int* __restrict__ tile_exp,
    const int* __restrict__ nrows_ptr,
    int layer)
{
    const int tm = blockIdx.x;
    const int tn = blockIdx.y;
    if (MODE >= 2) {
        if ((tm << 7) >= nrows_ptr[0]) return;   // tile fully padding
    }
    const unsigned short* Wl = W;
    const float* bl = bias;
    if (MODE >= 2) {
        const int e = tile_exp[tm];
        const int li = e * 4 + layer;
        Wl = W + ((size_t)li << 18);     // *512*512
        bl = bias + (li << 9);           // *512
    }
    const int tid = threadIdx.x;
    const int srow = tid & 127;
    const int kb = tid >> 7;             // 0/1: which k-subblock this thread stages

    size_t arow;
    if (MODE == 2) {
        const int p = perm[(tm << 7) + srow];
        arow = ((size_t)(p < 0 ? 0 : p)) << 9;
    } else {
        arow = ((size_t)((tm << 7) + srow)) << 9;
    }
    const unsigned short* Ap = A + arow;
    const unsigned short* Wp = Wl + (((size_t)((tn << 7) + srow)) << 9);

    // k-blocked LDS layout: elem offset (row,k) = (k>>3)*1024 + row*8 + (k&7)
    // -> ds_read_b128 of a fragment is bank-conflict-free (2 lanes/bank)
    __shared__ __align__(16) unsigned short lsA[8192];
    __shared__ __align__(16) unsigned short lsB[8192];

    f32x4 acc[4][4];
#pragma unroll
    for (int i = 0; i < 4; ++i)
#pragma unroll
        for (int j = 0; j < 4; ++j)
            acc[i][j] = f32x4{0.f, 0.f, 0.f, 0.f};

    const int lane = tid & 63;
    const int wv = tid >> 6;
    const int wm = wv >> 1;
    const int wn = wv & 1;
    const int lr = lane & 15;
    const int kg = lane >> 4;
    const int r0 = (wm << 6) + lr;
    const int c0 = (wn << 6) + lr;

    for (int ko = 0; ko < 8; ++ko) {
        __syncthreads();
        const int kcol = ko << 6;
#pragma unroll
        for (int c = 0; c < 4; ++c) {
            const int k0 = kcol + ((2 * c + kb) << 3);    // global k of this 16B chunk
            const int lo = (c << 11) + (tid << 3);        // linear LDS dest (lane-ordered)
            gld16(Ap + k0, &lsA[lo]);
            gld16(Wp + k0, &lsB[lo]);
        }
        __syncthreads();
#pragma unroll
        for (int kk = 0; kk < 2; ++kk) {
            const int kbo = (((kk << 2) + kg) << 10);     // k-block base (elems)
            bf16x8 af[4], bv[4];
#pragma unroll
            for (int i = 0; i < 4; ++i)
                af[i] = *reinterpret_cast<const bf16x8*>(&lsA[kbo + ((r0 + (i << 4)) << 3)]);
#pragma unroll
            for (int j = 0; j < 4; ++j)
                bv[j] = *reinterpret_cast<const bf16x8*>(&lsB[kbo + ((c0 + (j << 4)) << 3)]);
#pragma unroll
            for (int i = 0; i < 4; ++i)
#pragma unroll
                for (int j = 0; j < 4; ++j)
                    acc[i][j] = __builtin_amdgcn_mfma_f32_16x16x32_bf16(af[i], bv[j], acc[i][j], 0, 0, 0);
        }
    }

    // epilogue; D layout: col = lane&15, row = (lane>>4)*4 + reg   [m89 verified]
    const int colb = (tn << 7) + (wn << 6);
    const int rowb = (tm << 7) + (wm << 6);
#pragma unroll
    for (int j = 0; j < 4; ++j) {
        const int col = colb + (j << 4) + lr;
        const float bj = bl[col];
#pragma unroll
        for (int i = 0; i < 4; ++i) {
            const int rb = rowb + (i << 4) + (kg << 2);
#pragma unroll
            for (int r = 0; r < 4; ++r) {
                const int row = rb + r;
                float v = acc[i][j][r] + bj;
                if (MODE == 0 || MODE == 2 || MODE == 3) {
                    v = fmaxf(v, 0.f);
                    outb[((size_t)row << 9) + col] = f2bf(v);
                } else if (MODE == 1) {
                    v = fmaxf(v, 0.f);                       // h = s_unrelated
                    const size_t gi = ((size_t)row << 9) + col;
                    const float sv = sf32[gi];
                    outb[gi] = f2bf(sv - v);                 // s_related
                    outb2[gi] = f2bf(v);                     // s_unrelated
                } else {                                     // MODE 4
                    const int b = perm[row];
                    if (b >= 0) {
                        const size_t gi = ((size_t)b << 9) + col;
                        outf[gi] = v + bf2f(sunrel[gi]);
                    }
                }
            }
        }
    }
}

// ---------------- launch ----------------
extern "C" void kernel_launch(void* const* d_in, const int* in_sizes, int n_in,
                              void* d_out, int out_size, void* d_ws, size_t ws_size,
                              hipStream_t stream)
{
    const float* s     = (const float*)d_in[0];
    const int*   y     = (const int*)d_in[1];
    const float* dec_W = (const float*)d_in[2];
    const float* dec_b = (const float*)d_in[3];
    const float* exp_W = (const float*)d_in[4];
    const float* exp_b = (const float*)d_in[5];
    float* out = (float*)d_out;

    // workspace carve (~72.4 MB total)
    unsigned short* decWb = (unsigned short*)d_ws;              // 4*512*512 bf16
    unsigned short* expWb = decWb + 4 * 512 * 512;              // 32*512*512 bf16
    unsigned short* bufS  = expWb + 8 * 4 * 512 * 512;          // PR*512 bf16 (s_bf -> s_rel -> scratch)
    unsigned short* bufA  = bufS + (size_t)PR * 512;            // PR*512 bf16
    unsigned short* bufB  = bufA + (size_t)PR * 512;            // PR*512 bf16 (-> s_unrel)
    int* perm     = (int*)(bufB + (size_t)PR * 512);            // PR
    int* counts   = perm + PR;                                  // 8
    int* cursors  = counts + 8;                                 // 8
    int* starts   = cursors + 8;                                // 9 (starts[8]=total padded rows)
    int* tile_exp = starts + 9;                                 // MAXT

    cvt_bf16<<<512, 256, 0, stream>>>(dec_W, decWb, (4 * 512 * 512) / 4);
    cvt_bf16<<<2048, 256, 0, stream>>>(exp_W, expWb, (8 * 4 * 512 * 512) / 4);
    cvt_bf16<<<2048, 256, 0, stream>>>(s, bufS, (BB * 512) / 4);

    bucket_init<<<PR / 256, 256, 0, stream>>>(perm, counts, cursors, tile_exp);
    bucket_count<<<BB / 1024, 1024, 0, stream>>>(y, counts);
    bucket_scan<<<1, 64, 0, stream>>>(counts, starts, tile_exp);
    bucket_scatter<<<BB / 1024, 1024, 0, stream>>>(y, starts, cursors, perm);

    dim3 blk(256);
    dim3 gdec(BB / 128, 4);
    dim3 gexp(MAXT, 4);

    // decomposer: bufS -> bufA -> bufB -> bufA -> (s_rel in bufS, s_unrel in bufB)
    gemm_k<0><<<gdec, blk, 0, stream>>>(bufS, decWb, dec_b, bufA,
                                        nullptr, nullptr, nullptr, nullptr, nullptr, nullptr, nullptr, 0);
    gemm_k<0><<<gdec, blk, 0, stream>>>(bufA, decWb + (1u << 18), dec_b + 512, bufB,
                                        nullptr, nullptr, nullptr, nullptr, nullptr, nullptr, nullptr, 0);
    gemm_k<0><<<gdec, blk, 0, stream>>>(bufB, decWb + (2u << 18), dec_b + 1024, bufA,
                                        nullptr, nullptr, nullptr, nullptr, nullptr, nullptr, nullptr, 0);
    gemm_k<1><<<gdec, blk, 0, stream>>>(bufA, decWb + (3u << 18), dec_b + 1536, bufS,
                                        bufB, s, nullptr, nullptr, nullptr, nullptr, nullptr, 0);

    // experts (selected expert only, bucketed): gather bufS -> bufA -> bufS -> bufA -> d_out
    gemm_k<2><<<gexp, blk, 0, stream>>>(bufS, expWb, exp_b, bufA,
                                        nullptr, nullptr, nullptr, nullptr, perm, tile_exp, starts + 8, 0);
    gemm_k<3><<<gexp, blk, 0, stream>>>(bufA, expWb, exp_b, bufS,
                                        nullptr, nullptr, nullptr, nullptr, perm, tile_exp, starts + 8, 1);
    gemm_k<3><<<gexp, blk, 0, stream>>>(bufS, expWb, exp_b, bufA,
                                        nullptr, nullptr, nullptr, nullptr, perm, tile_exp, starts + 8, 2);
    gemm_k<4><<<gexp, blk, 0, stream>>>(bufA, expWb, exp_b, nullptr,
                                        nullptr, nullptr, out, bufB, perm, tile_exp, starts + 8, 3);
}

// Round 3
// 205.117 us; speedup vs baseline: 2.1426x; 1.4484x over previous
//
#include <hip/hip_runtime.h>
#include <stdint.h>

#define BB 16384
#define PR 17408      // 16384 + 8*128 worst-case bucket padding
#define MAXT 136      // PR/128

typedef short bf16x8 __attribute__((ext_vector_type(8)));
typedef float f32x4 __attribute__((ext_vector_type(4)));
typedef unsigned short us4v __attribute__((ext_vector_type(4)));

typedef __attribute__((address_space(1))) unsigned short gus_t;
typedef __attribute__((address_space(3))) unsigned short lus_t;

__device__ __forceinline__ unsigned short f2bf(float f) {
    unsigned int u = __float_as_uint(f);
    u += 0x7fffu + ((u >> 16) & 1u);   // RNE
    return (unsigned short)(u >> 16);
}
__device__ __forceinline__ float bf2f(unsigned short h) {
    return __uint_as_float(((unsigned int)h) << 16);
}

__device__ __forceinline__ void gld16(const unsigned short* g, unsigned short* l) {
    __builtin_amdgcn_global_load_lds(
        reinterpret_cast<const gus_t*>(reinterpret_cast<uintptr_t>(g)),
        reinterpret_cast<lus_t*>(reinterpret_cast<uintptr_t>(l)),
        16, 0, 0);
}

// ---------------- conversion ----------------
__global__ void cvt_bf16(const float* __restrict__ src, unsigned short* __restrict__ dst, int n4) {
    int stride = gridDim.x * blockDim.x;
    for (int i = blockIdx.x * blockDim.x + threadIdx.x; i < n4; i += stride) {
        f32x4 v = reinterpret_cast<const f32x4*>(src)[i];
        us4v o;
        o[0] = f2bf(v[0]); o[1] = f2bf(v[1]); o[2] = f2bf(v[2]); o[3] = f2bf(v[3]);
        reinterpret_cast<us4v*>(dst)[i] = o;
    }
}

// ---------------- bucketing (block-aggregated atomics) ----------------
__global__ void bucket_init(int* perm, int* counts, int* cursors, int* tile_exp) {
    int i = blockIdx.x * blockDim.x + threadIdx.x;
    if (i < PR) perm[i] = -1;
    if (i < 8) { counts[i] = 0; cursors[i] = 0; }
    if (i < MAXT) tile_exp[i] = 0;
}

__global__ __launch_bounds__(1024) void bucket_count(const int* __restrict__ y, int* counts) {
    __shared__ int lc[8];
    const int t = threadIdx.x;
    if (t < 8) lc[t] = 0;
    __syncthreads();
    atomicAdd(&lc[y[blockIdx.x * 1024 + t]], 1);
    __syncthreads();
    if (t < 8) atomicAdd(&counts[t], lc[t]);
}

__global__ void bucket_scan(const int* __restrict__ counts, int* starts, int* tile_exp) {
    if (threadIdx.x == 0 && blockIdx.x == 0) {
        int s = 0;
        for (int e = 0; e < 8; ++e) {
            starts[e] = s;
            int nt = (counts[e] + 127) >> 7;
            for (int t = 0; t < nt; ++t) tile_exp[(s >> 7) + t] = e;
            s += nt << 7;
        }
        starts[8] = s;
    }
}

__global__ __launch_bounds__(1024) void bucket_scatter(const int* __restrict__ y,
                                                       const int* __restrict__ starts,
                                                       int* cursors, int* perm) {
    __shared__ int lc[8];
    __shared__ int lbase[8];
    const int t = threadIdx.x;
    if (t < 8) lc[t] = 0;
    __syncthreads();
    const int i = blockIdx.x * 1024 + t;
    const int e = y[i];
    const int r = atomicAdd(&lc[e], 1);
    __syncthreads();
    if (t < 8) lbase[t] = atomicAdd(&cursors[t], lc[t]);
    __syncthreads();
    perm[starts[e] + lbase[e] + r] = i;
}

// ---------------- GEMM: C[M,512] = A[M,512] * W[512,512]^T (+bias, epilogue) ----------
// LDS tile layout: [128 rows][8 slots x 8 bf16], logical chunk kc stored at slot
// kc ^ (row&7) (bank-conflict-free ds_read_b128). Staged with LINEAR LDS dest +
// inverse-swizzled global source (global_load_lds writes base+lane*16 only).
// MODE 0: dense, relu -> bf16 out                            (dec layers 1-3)
// MODE 1: dense, relu -> h; srel=bf16(s-h); sunrel=bf16(h)   (dec layer 4)
// MODE 2: gather rows via perm, expert W, relu -> bf16       (exp layer 1)
// MODE 3: dense perm-space, expert W, relu -> bf16           (exp layers 2,3)
// MODE 4: dense perm-space, expert W, += sunrel, scatter f32 (exp layer 4)
template <int MODE>
__global__ __launch_bounds__(256) void gemm_k(
    const unsigned short* __restrict__ A,
    const unsigned short* __restrict__ W,
    const float* __restrict__ bias,
    unsigned short* __restrict__ outb,
    unsigned short* __restrict__ outb2,
    const float* __restrict__ sf32,
    float* __restrict__ outf,
    const unsigned short* __restrict__ sunrel,
    const int* __restrict__ perm,
    const int* __restrict__ tile_exp,
    const int* __restrict__ nrows_ptr,
    int layer)
{
    const int tm = blockIdx.x;
    const int tn = blockIdx.y;
    if (MODE >= 2) {
        if ((tm << 7) >= nrows_ptr[0]) return;
    }
    const unsigned short* Wl = W;
    const float* bl = bias;
    if (MODE >= 2) {
        const int e = tile_exp[tm];
        const int li = e * 4 + layer;
        Wl = W + ((size_t)li << 18);
        bl = bias + (li << 9);
    }
    const int tid = threadIdx.x;

    __shared__ __align__(16) unsigned short ls[32768];   // 64KB: 2 x (A 16KB + B 16KB)

    // staging: chunk idx = c*256+tid -> row = c*32+(tid>>3), slot = tid&7
    // inverse swizzle: source kchunk = slot ^ (row&7); (row&7)==((tid>>3)&7) for all c
    const int srow = tid >> 3;                              // 0..31
    const int kc8  = (((tid & 7) ^ (srow & 7)) << 3);       // source k elem offset in [0,64)
    size_t aoff[4], boff[4];
#pragma unroll
    for (int c = 0; c < 4; ++c) {
        const int rl = (c << 5) + srow;                     // 0..127
        int ra;
        if (MODE == 2) {
            const int p = perm[(tm << 7) + rl];
            ra = (p < 0) ? 0 : p;
        } else {
            ra = (tm << 7) + rl;
        }
        aoff[c] = ((size_t)ra << 9) + kc8;
        boff[c] = ((size_t)((tn << 7) + rl) << 9) + kc8;
    }

    f32x4 acc[4][4];
#pragma unroll
    for (int i = 0; i < 4; ++i)
#pragma unroll
        for (int j = 0; j < 4; ++j)
            acc[i][j] = f32x4{0.f, 0.f, 0.f, 0.f};

    const int lane = tid & 63;
    const int wv = tid >> 6;
    const int wm = wv >> 1;
    const int wn = wv & 1;
    const int lr = lane & 15;
    const int kg = lane >> 4;
    const int xorf = lr & 7;                                // (frag row)&7 == lr&7
    const int ar0 = (((wm << 6) + lr) << 6);                // row*64 elems
    const int br0 = (((wn << 6) + lr) << 6);

#define STAGE(ko_, buf_) do {                                          \
    const int kcol_ = (ko_) << 6;                                      \
    unsigned short* lA_ = ls + ((buf_) << 14);                         \
    unsigned short* lB_ = lA_ + 8192;                                  \
    gld16(A  + aoff[0] + kcol_, lA_ + (tid << 3));                     \
    gld16(Wl + boff[0] + kcol_, lB_ + (tid << 3));                     \
    gld16(A  + aoff[1] + kcol_, lA_ + 2048 + (tid << 3));              \
    gld16(Wl + boff[1] + kcol_, lB_ + 2048 + (tid << 3));              \
    gld16(A  + aoff[2] + kcol_, lA_ + 4096 + (tid << 3));              \
    gld16(Wl + boff[2] + kcol_, lB_ + 4096 + (tid << 3));              \
    gld16(A  + aoff[3] + kcol_, lA_ + 6144 + (tid << 3));              \
    gld16(Wl + boff[3] + kcol_, lB_ + 6144 + (tid << 3));              \
} while (0)

    STAGE(0, 0);
    __syncthreads();                 // drains stage(0)

    for (int ko = 0; ko < 8; ++ko) {
        if (ko < 7) STAGE(ko + 1, (ko + 1) & 1);   // prefetch flies under compute
        const unsigned short* lA = ls + ((ko & 1) << 14);
        const unsigned short* lB = lA + 8192;
#pragma unroll
        for (int kk = 0; kk < 2; ++kk) {
            const int sl = ((((kk << 2) + kg) ^ xorf) << 3);   // swizzled slot
            bf16x8 af[4], bv[4];
#pragma unroll
            for (int i = 0; i < 4; ++i)
                af[i] = *reinterpret_cast<const bf16x8*>(&lA[ar0 + (i << 10) + sl]);
#pragma unroll
            for (int j = 0; j < 4; ++j)
                bv[j] = *reinterpret_cast<const bf16x8*>(&lB[br0 + (j << 10) + sl]);
#pragma unroll
            for (int i = 0; i < 4; ++i)
#pragma unroll
                for (int j = 0; j < 4; ++j)
                    acc[i][j] = __builtin_amdgcn_mfma_f32_16x16x32_bf16(af[i], bv[j], acc[i][j], 0, 0, 0);
        }
        __syncthreads();             // drains next-tile loads + all ds reads
    }

    // ---- epilogue; D layout: col = lane&15, row = (lane>>4)*4 + reg ----
    if (MODE == 4) {
        // f32 scatter: 16 lanes x consecutive f32 cols = full 64B lines already
        const int colb = (tn << 7) + (wn << 6);
        const int rowb = (tm << 7) + (wm << 6);
#pragma unroll
        for (int j = 0; j < 4; ++j) {
            const int col = colb + (j << 4) + lr;
            const float bj = bl[col];
#pragma unroll
            for (int i = 0; i < 4; ++i) {
                const int rb = rowb + (i << 4) + (kg << 2);
#pragma unroll
                for (int r = 0; r < 4; ++r) {
                    const int row = rb + r;
                    const int b = perm[row];
                    if (b >= 0) {
                        const size_t gi = ((size_t)b << 9) + col;
                        outf[gi] = acc[i][j][r] + bj + bf2f(sunrel[gi]);
                    }
                }
            }
        }
        return;
    }

    // bf16 modes: transpose through LDS (swizzled) -> 16B/lane coalesced stores
#pragma unroll
    for (int j = 0; j < 4; ++j) {
        const int cl = (wn << 6) + (j << 4) + lr;
        const float bj = bl[(tn << 7) + cl];
#pragma unroll
        for (int i = 0; i < 4; ++i) {
#pragma unroll
            for (int r = 0; r < 4; ++r) {
                const int rl = (wm << 6) + (i << 4) + (kg << 2) + r;
                float v = acc[i][j][r] + bj;
                v = fmaxf(v, 0.f);                          // all bf16 modes relu
                ls[(rl << 7) + (cl ^ ((rl & 7) << 3))] = f2bf(v);
            }
        }
    }
    __syncthreads();
#pragma unroll
    for (int c = 0; c < 8; ++c) {
        const int idx = (c << 8) + tid;
        const int rl = idx >> 4;
        const int ch = idx & 15;
        bf16x8 v8 = *reinterpret_cast<const bf16x8*>(&ls[(rl << 7) + ((ch ^ (rl & 7)) << 3)]);
        const size_t gi = (((size_t)((tm << 7) + rl)) << 9) + (tn << 7) + (ch << 3);
        if (MODE == 1) {
            *reinterpret_cast<bf16x8*>(&outb2[gi]) = v8;    // s_unrelated = h
            f32x4 s0 = *reinterpret_cast<const f32x4*>(&sf32[gi]);
            f32x4 s1 = *reinterpret_cast<const f32x4*>(&sf32[gi + 4]);
            bf16x8 sr;
#pragma unroll
            for (int m = 0; m < 4; ++m) {
                sr[m]     = (short)f2bf(s0[m] - bf2f((unsigned short)v8[m]));
                sr[m + 4] = (short)f2bf(s1[m] - bf2f((unsigned short)v8[m + 4]));
            }
            *reinterpret_cast<bf16x8*>(&outb[gi]) = sr;     // s_related
        } else {
            *reinterpret_cast<bf16x8*>(&outb[gi]) = v8;
        }
    }
#undef STAGE
}

// ---------------- launch ----------------
extern "C" void kernel_launch(void* const* d_in, const int* in_sizes, int n_in,
                              void* d_out, int out_size, void* d_ws, size_t ws_size,
                              hipStream_t stream)
{
    const float* s     = (const float*)d_in[0];
    const int*   y     = (const int*)d_in[1];
    const float* dec_W = (const float*)d_in[2];
    const float* dec_b = (const float*)d_in[3];
    const float* exp_W = (const float*)d_in[4];
    const float* exp_b = (const float*)d_in[5];
    float* out = (float*)d_out;

    unsigned short* decWb = (unsigned short*)d_ws;              // 4*512*512 bf16
    unsigned short* expWb = decWb + 4 * 512 * 512;              // 32*512*512 bf16
    unsigned short* bufS  = expWb + 8 * 4 * 512 * 512;          // PR*512 bf16
    unsigned short* bufA  = bufS + (size_t)PR * 512;            // PR*512 bf16
    unsigned short* bufB  = bufA + (size_t)PR * 512;            // PR*512 bf16 (-> s_unrel)
    int* perm     = (int*)(bufB + (size_t)PR * 512);            // PR
    int* counts   = perm + PR;                                  // 8
    int* cursors  = counts + 8;                                 // 8
    int* starts   = cursors + 8;                                // 9
    int* tile_exp = starts + 9;                                 // MAXT

    cvt_bf16<<<512, 256, 0, stream>>>(dec_W, decWb, (4 * 512 * 512) / 4);
    cvt_bf16<<<2048, 256, 0, stream>>>(exp_W, expWb, (8 * 4 * 512 * 512) / 4);
    cvt_bf16<<<2048, 256, 0, stream>>>(s, bufS, (BB * 512) / 4);

    bucket_init<<<PR / 256, 256, 0, stream>>>(perm, counts, cursors, tile_exp);
    bucket_count<<<BB / 1024, 1024, 0, stream>>>(y, counts);
    bucket_scan<<<1, 64, 0, stream>>>(counts, starts, tile_exp);
    bucket_scatter<<<BB / 1024, 1024, 0, stream>>>(y, starts, cursors, perm);

    dim3 blk(256);
    dim3 gdec(BB / 128, 4);
    dim3 gexp(MAXT, 4);

    // decomposer: bufS -> bufA -> bufB -> bufA -> (s_rel in bufS, s_unrel in bufB)
    gemm_k<0><<<gdec, blk, 0, stream>>>(bufS, decWb, dec_b, bufA,
                                        nullptr, nullptr, nullptr, nullptr, nullptr, nullptr, nullptr, 0);
    gemm_k<0><<<gdec, blk, 0, stream>>>(bufA, decWb + (1u << 18), dec_b + 512, bufB,
                                        nullptr, nullptr, nullptr, nullptr, nullptr, nullptr, nullptr, 0);
    gemm_k<0><<<gdec, blk, 0, stream>>>(bufB, decWb + (2u << 18), dec_b + 1024, bufA,
                                        nullptr, nullptr, nullptr, nullptr, nullptr, nullptr, nullptr, 0);
    gemm_k<1><<<gdec, blk, 0, stream>>>(bufA, decWb + (3u << 18), dec_b + 1536, bufS,
                                        bufB, s, nullptr, nullptr, nullptr, nullptr, nullptr, 0);

    // experts: gather bufS -> bufA -> bufS -> bufA -> d_out
    gemm_k<2><<<gexp, blk, 0, stream>>>(bufS, expWb, exp_b, bufA,
                                        nullptr, nullptr, nullptr, nullptr, perm, tile_exp, starts + 8, 0);
    gemm_k<3><<<gexp, blk, 0, stream>>>(bufA, expWb, exp_b, bufS,
                                        nullptr, nullptr, nullptr, nullptr, perm, tile_exp, starts + 8, 1);
    gemm_k<3><<<gexp, blk, 0, stream>>>(bufS, expWb, exp_b, bufA,
                                        nullptr, nullptr, nullptr, nullptr, perm, tile_exp, starts + 8, 2);
    gemm_k<4><<<gexp, blk, 0, stream>>>(bufA, expWb, exp_b, nullptr,
                                        nullptr, nullptr, out, bufB, perm, tile_exp, starts + 8, 3);
}